// Round 7
// baseline (41673.172 us; speedup 1.0000x reference)
//
#include <hip/hip_runtime.h>
#include <cstdint>

#define BATCH 4096
#define LATENT 128
#define RNN 512
#define CODE 512
#define DISC 64
#define NSEG 64
#define UNPACK_COLS 130  // LATENT + INPUT

// ------------- threefry2x32, JAX partitionable mode, key = (0, 42) -----------
__device__ __forceinline__ uint32_t rotl32(uint32_t x, uint32_t r) {
  return (x << r) | (x >> (32u - r));
}

__device__ __forceinline__ uint32_t threefry_bits(uint32_t n) {
  const uint32_t k0 = 0u, k1 = 42u;
  const uint32_t ks2 = k0 ^ k1 ^ 0x1BD11BDAu;
  uint32_t x0 = 0u, x1 = n;
  x0 += k0; x1 += k1;
#define TF_ROUND(r) { x0 += x1; x1 = rotl32(x1, r); x1 ^= x0; }
  TF_ROUND(13) TF_ROUND(15) TF_ROUND(26) TF_ROUND(6)
  x0 += k1;  x1 += ks2 + 1u;
  TF_ROUND(17) TF_ROUND(29) TF_ROUND(16) TF_ROUND(24)
  x0 += ks2; x1 += k0 + 2u;
  TF_ROUND(13) TF_ROUND(15) TF_ROUND(26) TF_ROUND(6)
  x0 += k0;  x1 += k1 + 3u;
  TF_ROUND(17) TF_ROUND(29) TF_ROUND(16) TF_ROUND(24)
  x0 += k1;  x1 += ks2 + 4u;
  TF_ROUND(13) TF_ROUND(15) TF_ROUND(26) TF_ROUND(6)
  x0 += ks2; x1 += k0 + 5u;
#undef TF_ROUND
  return x0 ^ x1;
}

__device__ __forceinline__ float sigmoidf_(float v) {
  return 1.0f / (1.0f + expf(-v));
}

// ---------------- base = latent @ W_unpack[:, :128]^T + b_unpack --------------
__global__ __launch_bounds__(256) void base_kernel(
    const float* __restrict__ latent, const float* __restrict__ Wu,
    const float* __restrict__ bu, float* __restrict__ base) {
  __shared__ float lrow[LATENT];
  const int b = blockIdx.x;
  if (threadIdx.x < LATENT) lrow[threadIdx.x] = latent[b * LATENT + threadIdx.x];
  __syncthreads();
  for (int n = threadIdx.x; n < CODE; n += 256) {
    const float* wr = Wu + (size_t)n * UNPACK_COLS;
    float acc = 0.f;
#pragma unroll 8
    for (int k = 0; k < LATENT; ++k) acc += lrow[k] * wr[k];
    base[(size_t)b * CODE + n] = acc + bu[n];
  }
}

// ---------------- x = tanh(base + angle * W_unpack[:, 128]) -------------------
__global__ __launch_bounds__(256) void x_kernel(
    const float* __restrict__ base, const float* __restrict__ angle,
    const float* __restrict__ Wu, float* __restrict__ xo) {
  const int idx = blockIdx.x * 256 + threadIdx.x;
  const int b = idx >> 9;
  const int n = idx & 511;
  xo[idx] = tanhf(base[idx] + angle[b] * Wu[(size_t)n * UNPACK_COLS + 128]);
}

// ----- fused: gates = A1@W1^T + A2@W2^T + b1 + b2 ; (h,c) = LSTM(gates, c) ----
// Wave-uniform-A structure: 512 threads = 8 waves; wave w owns M-rows
// rowBase + 8w .. +8 -> A-fragments are wave-uniform BROADCAST global loads
// (1 cache line, no LDS, no per-lane VMEM cost).  LDS carries only W
// ([16 k][512 n], 32 KB): per kk each lane does 2 contiguous conflict-free
// ds_read_b128 (cols 4*lane and 256+4*lane).  Per-CU per kk: LDS ~128 cyc
// < FMA 256 cyc -> FMA-issue-bound (previous rounds: 4 reads/kk -> LDS-bound).
// Tile cols t in [0,512) map to gate (t>>7), rnncol bx*128 + (t&127); lane
// pair (l, l+32) holds (i,g)/(f,o) -> one shfl_xor(32) LSTM epilogue.
// k strictly ascending per output: accumulation order bit-identical to r2-r6.
#define BMW 64
#define KSTEP 16

__global__ __launch_bounds__(512, 2) void gemm_lstm(
    const float* __restrict__ A1, const float* __restrict__ W1,
    const float* __restrict__ A2, const float* __restrict__ W2,
    const float* __restrict__ b1, const float* __restrict__ b2,
    float* __restrict__ c_io, float* __restrict__ h_out) {
  __shared__ __align__(16) float Ws[KSTEP][512];  // 32 KB
  const int tid = threadIdx.x;
  const int lane = tid & 63;
  const int wv = tid >> 6;  // 0..7
  // de-swizzle blockIdx so each XCD-pair serves one bx (W L2-locality):
  const int d = blockIdx.x;                   // 0..255
  const int bx = (d & 7) >> 1;                // 0..3 rnncol-block
  const int by = ((d >> 3) << 1) | (d & 1);   // 0..63 M-tile
  const int rowBase = by * BMW;

  // W staging: thread owns tile-row t=tid; wn = global W row (gate-tiled)
  const int wn = ((tid >> 7) * RNN) + (bx << 7) + (tid & 127);
  const float* __restrict__ wrow1 = W1 + (size_t)wn * RNN;
  const float* __restrict__ wrow2 = W2 + (size_t)wn * RNN;

  float acc[8][8];
#pragma unroll
  for (int i = 0; i < 8; ++i)
#pragma unroll
    for (int j = 0; j < 8; ++j) acc[i][j] = 0.f;

  for (int seg = 0; seg < 2; ++seg) {
    const float* __restrict__ A = seg ? A2 : A1;
    const float* __restrict__ wrow = seg ? wrow2 : wrow1;
    float4 st[4];
#pragma unroll
    for (int q = 0; q < 4; ++q) st[q] = *(const float4*)&wrow[q * 4];

    for (int k0 = 0; k0 < RNN; k0 += KSTEP) {
      __syncthreads();  // previous step's readers done
#pragma unroll
      for (int q = 0; q < 4; ++q) {
        Ws[q * 4 + 0][tid] = st[q].x;
        Ws[q * 4 + 1][tid] = st[q].y;
        Ws[q * 4 + 2][tid] = st[q].z;
        Ws[q * 4 + 3][tid] = st[q].w;
      }
      __syncthreads();
      if (k0 + KSTEP < RNN) {
#pragma unroll
        for (int q = 0; q < 4; ++q)
          st[q] = *(const float4*)&wrow[k0 + KSTEP + q * 4];
      }
      const float* __restrict__ abase = A + (size_t)(rowBase + wv * 8) * RNN + k0;
#pragma unroll
      for (int c4 = 0; c4 < 4; ++c4) {
        float4 af[8];
#pragma unroll
        for (int i = 0; i < 8; ++i)
          af[i] = *(const float4*)&abase[(size_t)i * RNN + c4 * 4];  // broadcast
        float4 wfA[4], wfB[4];
#pragma unroll
        for (int kk = 0; kk < 4; ++kk) {
          wfA[kk] = *(const float4*)&Ws[c4 * 4 + kk][4 * lane];
          wfB[kk] = *(const float4*)&Ws[c4 * 4 + kk][256 + 4 * lane];
        }
#pragma unroll
        for (int kk = 0; kk < 4; ++kk) {
#pragma unroll
          for (int i = 0; i < 8; ++i) {
            const float a = ((const float*)&af[i])[kk];
            acc[i][0] += a * wfA[kk].x;
            acc[i][1] += a * wfA[kk].y;
            acc[i][2] += a * wfA[kk].z;
            acc[i][3] += a * wfA[kk].w;
            acc[i][4] += a * wfB[kk].x;
            acc[i][5] += a * wfB[kk].y;
            acc[i][6] += a * wfB[kk].z;
            acc[i][7] += a * wfB[kk].w;
          }
        }
      }
    }
  }

  // ---- fused LSTM epilogue ----
  // Own cols: tA = 4*lane (gate gA = lane>>5: 0=i or 1=f), tB = 256+4*lane
  // (gate gB = 2+(lane>>5): 2=g or 3=o).  rnncol c = bx*128 + 4*(lane&31)+j.
  // Partner lane^32 has the complementary gates for the SAME (rows, cols).
  const int col0 = (bx << 7) + 4 * (lane & 31);
  const int gA = lane >> 5;      // 0 or 1
  const int gB = 2 + gA;         // 2 or 3
  float bsA[4], bsB[4];
#pragma unroll
  for (int j = 0; j < 4; ++j) {
    bsA[j] = b1[gA * RNN + col0 + j] + b2[gA * RNN + col0 + j];
    bsB[j] = b1[gB * RNN + col0 + j] + b2[gB * RNN + col0 + j];
  }
  const bool low = (lane < 32);
#pragma unroll
  for (int i = 0; i < 8; ++i) {
    float vA[4], vB[4], pA[4], pB[4];
#pragma unroll
    for (int j = 0; j < 4; ++j) {
      vA[j] = acc[i][j] + bsA[j];
      vB[j] = acc[i][4 + j] + bsB[j];
      pA[j] = __shfl_xor(vA[j], 32);
      pB[j] = __shfl_xor(vB[j], 32);
    }
    const bool mine = low ? (i < 4) : (i >= 4);
    if (mine) {
      const int row = rowBase + wv * 8 + i;
      const size_t off = (size_t)row * RNN + col0;
      const float4 cold = *(const float4*)&c_io[off];
      const float co[4] = {cold.x, cold.y, cold.z, cold.w};
      float cn[4], hn[4];
#pragma unroll
      for (int j = 0; j < 4; ++j) {
        const float fi = low ? vA[j] : pA[j];
        const float ff = low ? pA[j] : vA[j];
        const float fg = low ? vB[j] : pB[j];
        const float fo = low ? pB[j] : vB[j];
        const float c2 = sigmoidf_(ff) * co[j] + sigmoidf_(fi) * tanhf(fg);
        cn[j] = c2;
        hn[j] = sigmoidf_(fo) * tanhf(c2);
      }
      *(float4*)&c_io[off] = make_float4(cn[0], cn[1], cn[2], cn[3]);
      *(float4*)&h_out[off] = make_float4(hn[0], hn[1], hn[2], hn[3]);
    }
  }
}

// -------- head: logits -> +gumbel -> softmax -> hard argmax -> angle ----------
__global__ __launch_bounds__(64) void head_kernel(
    const float* __restrict__ h1, const float* __restrict__ Wang,
    const float* __restrict__ bang, float* __restrict__ angle,
    float* __restrict__ out, int s) {
  const int b = blockIdx.x;
  const int d = threadIdx.x;
  const float4* hr = (const float4*)(h1 + (size_t)b * RNN);
  const float4* wr = (const float4*)(Wang + (size_t)d * RNN);
  float acc = 0.f;
#pragma unroll 16
  for (int k = 0; k < RNN / 4; ++k) {
    float4 a = hr[k], w = wr[k];
    acc += a.x * w.x; acc += a.y * w.y; acc += a.z * w.z; acc += a.w * w.w;
  }
  float z = acc + bang[d];
  const uint32_t n = ((uint32_t)s * BATCH + (uint32_t)b) * DISC + (uint32_t)d;
  const uint32_t bits = threefry_bits(n);
  const float f = __uint_as_float((bits >> 9) | 0x3f800000u) - 1.0f;
  const float u = fmaxf(1e-8f, f + 1e-8f);
  const float gum = -logf(-logf(u));
  z += gum;
  float m = z;
#pragma unroll
  for (int off = 32; off; off >>= 1) m = fmaxf(m, __shfl_xor(m, off));
  const float e = expf(z - m);
  float ssum = e;
#pragma unroll
  for (int off = 32; off; off >>= 1) ssum += __shfl_xor(ssum, off);
  const float y = e / ssum;
  float ymax = y;
#pragma unroll
  for (int off = 32; off; off >>= 1) ymax = fmaxf(ymax, __shfl_xor(ymax, off));
  const unsigned long long mask = __ballot(y == ymax);
  const int k = __ffsll(mask) - 1;
  if (d == 0) {
    const float sp = -1.0f + (2.0f / 63.0f) * (float)k;  // linspace(-1,1,64)[k]
    angle[b] = sp;
    out[((size_t)b * NSEG + s) * 2 + 0] = sp;
    out[((size_t)b * NSEG + s) * 2 + 1] = 0.0f;
  }
}

// ------------------------------- launch ---------------------------------------
extern "C" void kernel_launch(void* const* d_in, const int* in_sizes, int n_in,
                              void* d_out, int out_size, void* d_ws, size_t ws_size,
                              hipStream_t stream) {
  const float* latent   = (const float*)d_in[0];
  const float* W_unpack = (const float*)d_in[1];
  const float* b_unpack = (const float*)d_in[2];
  const float* Wih0     = (const float*)d_in[3];
  const float* Whh0     = (const float*)d_in[4];
  const float* bih0     = (const float*)d_in[5];
  const float* bhh0     = (const float*)d_in[6];
  const float* Wih1     = (const float*)d_in[7];
  const float* Whh1     = (const float*)d_in[8];
  const float* bih1     = (const float*)d_in[9];
  const float* bhh1     = (const float*)d_in[10];
  const float* W_angle  = (const float*)d_in[11];
  const float* b_angle  = (const float*)d_in[12];
  float* out = (float*)d_out;

  const size_t HC = (size_t)BATCH * RNN;  // 2M floats
  float* ws    = (float*)d_ws;
  float* h0a   = ws;
  float* h1a   = h0a + HC;
  float* c0    = h1a + HC;
  float* c1    = c0 + HC;
  float* angle = c1 + HC;                 // BATCH floats
  float* h0b   = angle + BATCH;
  float* h1b   = h0b + HC;
  float* x     = h1b + HC;
  float* base  = x + (size_t)BATCH * CODE;

  // zero the step-0-read state: h0a, h1a, c0, c1, angle (contiguous)
  hipMemsetAsync(ws, 0, (4 * HC + BATCH) * sizeof(float), stream);

  base_kernel<<<BATCH, 256, 0, stream>>>(latent, W_unpack, b_unpack, base);

  for (int s = 0; s < NSEG; ++s) {
    const int p = s & 1;
    float* h0p = p ? h0b : h0a; float* h0n = p ? h0a : h0b;
    float* h1p = p ? h1b : h1a; float* h1n = p ? h1a : h1b;
    x_kernel<<<(BATCH * CODE) / 256, 256, 0, stream>>>(base, angle, W_unpack, x);
    gemm_lstm<<<256, 512, 0, stream>>>(x, Wih0, h0p, Whh0, bih0, bhh0, c0, h0n);
    gemm_lstm<<<256, 512, 0, stream>>>(h0n, Wih1, h1p, Whh1, bih1, bhh1, c1, h1n);
    head_kernel<<<BATCH, 64, 0, stream>>>(h1n, W_angle, b_angle, angle, out, s);
  }
}